// Round 5
// baseline (722.754 us; speedup 1.0000x reference)
//
#include <hip/hip_runtime.h>
#include <math.h>

// Problem constants
#define TB 4
#define TS 2048
#define TE 1024
#define TH 16
#define TD 64
#define TM_ (TB*TS)   // 8192 rows

// Workspace float offsets
#define WS_Q   0
#define WS_K   8388608
#define WS_L   16777216
#define WS_TAB 16908288

typedef __attribute__((ext_vector_type(8))) short bf16x8;  // 8 bf16 = 4 VGPRs
typedef __attribute__((ext_vector_type(4))) float f32x4;

static __device__ inline unsigned fbits(float x) {
    union { float f; unsigned u; } v; v.f = x; return v.u;
}
static __device__ inline float bits2f(unsigned u) {
    union { unsigned u; float f; } v; v.u = u; return v.f;
}
static __device__ inline unsigned pack_rhu(float a, float b) {
    return __builtin_amdgcn_perm(fbits(b) + 0x8000u, fbits(a) + 0x8000u, 0x07060302u);
}
static __device__ inline short bf16s(float x) {
    return (short)((fbits(x) + 0x8000u) >> 16);
}
// hi/lo split: hp = packed (rounded) hi bf16s, lp = packed lo bf16s
static __device__ inline void split2(float x0, float x1, unsigned& hp, unsigned& lp) {
    unsigned u0 = fbits(x0) + 0x8000u, u1 = fbits(x1) + 0x8000u;
    hp = __builtin_amdgcn_perm(u1, u0, 0x07060302u);
    float h0 = bits2f(u0 & 0xffff0000u);
    float h1 = bits2f(u1 & 0xffff0000u);
    lp = pack_rhu(x0 - h0, x1 - h1);
}

// async 16B/lane global->LDS copy; lds_base is wave-uniform, HW adds lane*16
static __device__ inline void gl_lds16(const short* g, short* lds_base, int lane)
{
#if __has_builtin(__builtin_amdgcn_global_load_lds)
    __builtin_amdgcn_global_load_lds(
        (const __attribute__((address_space(1))) unsigned int*)g,
        (__attribute__((address_space(3))) unsigned int*)lds_base, 16, 0, 0);
#else
    *(uint4*)(lds_base + lane * 8) = *(const uint4*)g;
#endif
}

// ----------------------------------------------------------------------------
// split-row body: 32 fp32 -> merged 64sh tile: slots 0..7 (16B each),
// slot = chunk ^ key; chunks 0-3 = hi of k=c*8..c*8+8, chunks 4-7 = lo.
// ----------------------------------------------------------------------------
static __device__ inline void split_tile(const float* sp, short* dp, int key)
{
    unsigned H[16], L[16];
    #pragma unroll
    for (int c2 = 0; c2 < 8; ++c2) {
        float4 v = *(const float4*)(sp + c2 * 4);
        split2(v.x, v.y, H[2 * c2],     L[2 * c2]);
        split2(v.z, v.w, H[2 * c2 + 1], L[2 * c2 + 1]);
    }
    #pragma unroll
    for (int c = 0; c < 4; ++c) {
        *(uint4*)(dp + ((c ^ key) * 8)) =
            make_uint4(H[4 * c], H[4 * c + 1], H[4 * c + 2], H[4 * c + 3]);
        *(uint4*)(dp + (((4 + c) ^ key) * 8)) =
            make_uint4(L[4 * c], L[4 * c + 1], L[4 * c + 2], L[4 * c + 3]);
    }
}

// xsplit: [8192][1024] fp32 -> [8192][32 kt][8 slots * 8sh]. In-place safe
// (each thread reads+writes the same 128B region; no __restrict__).
__global__ __launch_bounds__(256, 4)
void xsplit(const float* src, short* dst)
{
    const int idx = blockIdx.x * 256 + threadIdx.x;   // 131072
    const int kt = idx & 15;                          // covers 2 tiles below
    const int row = idx >> 4;
    const float* sp = src + (size_t)row * 1024 + kt * 64;
    short* dp = dst + (size_t)row * 2048 + kt * 128;
    const int key = row & 7;
    split_tile(sp,      dp,      key);
    split_tile(sp + 32, dp + 64, key);
}

// wsplit: 4 weight matrices -> same layout, rows 0..4095
__global__ __launch_bounds__(256, 4)
void wsplit(const float* __restrict__ W0, const float* __restrict__ W1,
            const float* __restrict__ W2, const float* __restrict__ W3,
            short* __restrict__ dst)
{
    const int idx = blockIdx.x * 256 + threadIdx.x;   // 65536
    const int kt = idx & 15;
    const int row = idx >> 4;                          // 0..4095
    const int w = row >> 10, n = row & 1023;
    const float* Wx = (w == 0) ? W0 : (w == 1) ? W1 : (w == 2) ? W2 : W3;
    const float* sp = Wx + (size_t)n * 1024 + kt * 64;
    short* dp = dst + (size_t)row * 2048 + kt * 128;
    const int key = n & 7;
    split_tile(sp,      dp,      key);
    split_tile(sp + 32, dp + 64, key);
}

// ----------------------------------------------------------------------------
// GEMM R5: pre-split X and W, global_load_lds staging, swizzled LDS reads.
// C[m,n] = sum_k X[m,k]*W[n,k] + bias[n], 3-term split-bf16 MFMA, 128x128.
// MODE 0: fp32 out[m*N+n]; MODE 1: fp32 [B,H,S,D]; MODE 2: bf16 V^T [B,H,D,S]
// ----------------------------------------------------------------------------
template<int MODE>
__global__ __launch_bounds__(256, 3)
void gemm_nt(const short* __restrict__ Xs, const short* __restrict__ Ws,
             const float* __restrict__ bias, float* __restrict__ out)
{
    __shared__ short A2[128 * 64];
    __shared__ short B2[128 * 64];

    const int tid  = threadIdx.x;
    const int lane = tid & 63;
    const int wv   = tid >> 6;
    const int t16  = lane & 15;
    const int quad = lane >> 4;
    const int wm   = (wv >> 1) * 64;
    const int wn   = (wv & 1) * 64;
    const int m0 = blockIdx.y * 128;
    const int n0 = blockIdx.x * 128;

    const int grow = wv * 8 + (lane >> 3);   // 0..31 staging row within round
    const int gso  = (lane & 7) * 8;         // slot short-offset
    const int cxh = ((quad) ^ (t16 & 7)) * 8;
    const int cxl = ((4 + quad) ^ (t16 & 7)) * 8;

    f32x4 acc[4][4];
    #pragma unroll
    for (int i = 0; i < 4; ++i)
        #pragma unroll
        for (int j = 0; j < 4; ++j) acc[i][j] = (f32x4){0.f, 0.f, 0.f, 0.f};

    for (int kt = 0; kt < 32; ++kt) {
        __syncthreads();   // prev iter's LDS reads done
        #pragma unroll
        for (int r = 0; r < 4; ++r) {
            gl_lds16(Xs + (size_t)(m0 + r * 32 + grow) * 2048 + kt * 64 + gso,
                     &A2[(r * 32 + wv * 8) * 64], lane);
            gl_lds16(Ws + (size_t)(n0 + r * 32 + grow) * 2048 + kt * 64 + gso,
                     &B2[(r * 32 + wv * 8) * 64], lane);
        }
        __syncthreads();   // vmcnt(0) drain -> tile ready

        bf16x8 ah[4], al[4], bh[4], bl[4];
        #pragma unroll
        for (int i = 0; i < 4; ++i) {
            ah[i] = *(const bf16x8*)&A2[(wm + i * 16 + t16) * 64 + cxh];
            al[i] = *(const bf16x8*)&A2[(wm + i * 16 + t16) * 64 + cxl];
            bh[i] = *(const bf16x8*)&B2[(wn + i * 16 + t16) * 64 + cxh];
            bl[i] = *(const bf16x8*)&B2[(wn + i * 16 + t16) * 64 + cxl];
        }
        #pragma unroll
        for (int i = 0; i < 4; ++i)
            #pragma unroll
            for (int j = 0; j < 4; ++j) {
                acc[i][j] = __builtin_amdgcn_mfma_f32_16x16x32_bf16(ah[i], bh[j], acc[i][j], 0, 0, 0);
                acc[i][j] = __builtin_amdgcn_mfma_f32_16x16x32_bf16(al[i], bh[j], acc[i][j], 0, 0, 0);
                acc[i][j] = __builtin_amdgcn_mfma_f32_16x16x32_bf16(ah[i], bl[j], acc[i][j], 0, 0, 0);
            }
    }

    if (MODE == 2) {
        short* o16 = (short*)out;
        const int b = m0 >> 11;
        const int sbase0 = (m0 & 2047) + wm + quad * 4;
        #pragma unroll
        for (int j = 0; j < 4; ++j) {
            const int n = n0 + wn + j * 16 + t16;
            const int h = n >> 6, d = n & 63;
            const float bv = bias[n];
            const size_t base = ((size_t)(b * TH + h) * TD + d) * TS;
            #pragma unroll
            for (int i = 0; i < 4; ++i) {
                const int s = sbase0 + i * 16;
                uint2 p = make_uint2(pack_rhu(acc[i][j][0] + bv, acc[i][j][1] + bv),
                                     pack_rhu(acc[i][j][2] + bv, acc[i][j][3] + bv));
                *(uint2*)(o16 + base + s) = p;
            }
        }
        return;
    }

    #pragma unroll
    for (int j = 0; j < 4; ++j) {
        const int n = n0 + wn + j * 16 + t16;
        const float bv = bias[n];
        if (MODE == 0) {
            #pragma unroll
            for (int i = 0; i < 4; ++i)
                #pragma unroll
                for (int r = 0; r < 4; ++r) {
                    const int m = m0 + wm + i * 16 + quad * 4 + r;
                    out[(size_t)m * TE + n] = acc[i][j][r] + bv;
                }
        } else {
            const int h = n >> 6, d = n & 63;
            #pragma unroll
            for (int i = 0; i < 4; ++i)
                #pragma unroll
                for (int r = 0; r < 4; ++r) {
                    const int m = m0 + wm + i * 16 + quad * 4 + r;
                    const int bb_ = m >> 11, s = m & 2047;
                    out[((size_t)(bb_ * TH + h) * TS + s) * TD + d] = acc[i][j][r] + bv;
                }
        }
    }
}

// ----------------------------------------------------------------------------
__global__ void rope_table(float* __restrict__ tab)
{
    const int idx = blockIdx.x * 256 + threadIdx.x;
    const int d = idx & 31, s = idx >> 5;
    const float e = (float)(2 * d) / 64.0f;
    const float inv = 1.0f / powf(10000.0f, e);
    const float a = (float)s * inv;
    tab[2 * idx + 0] = cosf(a);
    tab[2 * idx + 1] = sinf(a);
}

// ----------------------------------------------------------------------------
// rope_split: in-place RoPE (+Q scale) then hi/lo split; BOTH Q and K rows
// chunk-swizzled (slot = ch ^ (s&7)) within each 64-short half.
// ----------------------------------------------------------------------------
__global__ __launch_bounds__(256, 2)
void rope_split(float* __restrict__ Q, float* __restrict__ Kv,
                const float* __restrict__ tab)
{
    const int idx = blockIdx.x * 256 + threadIdx.x;    // 262144 rows
    const int s  = idx & 2047;
    const int bh = (idx >> 11) & 63;
    const int qk = idx >> 17;
    float* P = qk ? Kv : Q;
    const float scale = qk ? 1.0f : (0.125f * 1.44269504f);
    const int key = s & 7;
    unsigned* rp = (unsigned*)(P + ((size_t)bh * TS + s) * 64);

    unsigned xu[64];
    #pragma unroll
    for (int i = 0; i < 16; ++i) {
        uint4 v = *(const uint4*)(rp + i * 4);
        xu[4 * i + 0] = v.x; xu[4 * i + 1] = v.y;
        xu[4 * i + 2] = v.z; xu[4 * i + 3] = v.w;
    }
    const float* tb = tab + (size_t)s * 64;
    #pragma unroll
    for (int d = 0; d < 32; ++d) {
        const float c = tb[2 * d], sn = tb[2 * d + 1];
        const float x0 = bits2f(xu[d]), x1 = bits2f(xu[d + 32]);
        xu[d]      = fbits((x0 * c - x1 * sn) * scale);
        xu[d + 32] = fbits((x1 * c + x0 * sn) * scale);
    }
    #pragma unroll
    for (int ch = 0; ch < 8; ++ch) {
        unsigned h[4], l[4];
        #pragma unroll
        for (int p = 0; p < 4; ++p)
            split2(bits2f(xu[ch * 8 + 2 * p]), bits2f(xu[ch * 8 + 2 * p + 1]), h[p], l[p]);
        const int slot = ch ^ key;
        *(uint4*)(rp + slot * 4)      = make_uint4(h[0], h[1], h[2], h[3]);
        *(uint4*)(rp + 32 + slot * 4) = make_uint4(l[0], l[1], l[2], l[3]);
    }
}

// ----------------------------------------------------------------------------
// Flash attention (R4-verified structure; only Q-frag addressing adapted to
// the now-swizzled Q rows). T14 reg prefetch + XCD remap + swizzled LDS.
// ----------------------------------------------------------------------------
__global__ __launch_bounds__(512, 4)
void attn_flash(const short* __restrict__ Qs, const short* __restrict__ Ks,
                const short* __restrict__ VT, float* __restrict__ O,
                float* __restrict__ Ls)
{
    __shared__ short KhL[4096], KlL[4096];
    __shared__ short VtL[4096];
    __shared__ short PsL[8192];

    const int tid  = threadIdx.x;
    const int lane = tid & 63;
    const int wv   = tid >> 6;
    const int t16  = lane & 15;
    const int quad = lane >> 4;
    const int q0w  = wv * 16;

    const int L   = blockIdx.x + 16 * blockIdx.y + 256 * blockIdx.z;
    const int xcd = L & 7;
    const int i_  = L >> 3;
    const int qt  = i_ & 15;
    const int g   = (xcd << 3) | (i_ >> 4);
    const int h   = g & 15;
    const int b   = g >> 4;

    const int q0 = qt * 128;
    const int bh = b * TH + h;
    const short* Krb = Ks + (size_t)bh * TS * 128;
    const short* Vth = VT + (size_t)bh * TD * TS;

    const int cx0 = ((quad) ^ (t16 & 7)) * 8;
    const int cx1 = ((4 + quad) ^ (t16 & 7)) * 8;

    // Q fragments (pre-scaled, pre-split, slot-swizzled by s&7 == t16&7)
    bf16x8 qfh[2], qfl[2];
    {
        const short* qrow = Qs + ((size_t)bh * TS + q0 + q0w + t16) * 128;
        qfh[0] = *(const bf16x8*)(qrow + cx0);
        qfh[1] = *(const bf16x8*)(qrow + cx1);
        qfl[0] = *(const bf16x8*)(qrow + 64 + cx0);
        qfl[1] = *(const bf16x8*)(qrow + 64 + cx1);
    }

    float lsum[4] = {0.f, 0.f, 0.f, 0.f};
    f32x4 o_acc[4];
    #pragma unroll
    for (int dt = 0; dt < 4; ++dt) o_acc[dt] = (f32x4){0.f, 0.f, 0.f, 0.f};

    const int krow = tid >> 3;
    const int kch  = tid & 7;
    const int ksl  = (kch ^ (krow & 7)) * 8;

    uint4 rkh = *(const uint4*)(Krb + (size_t)krow * 128 + kch * 8);
    uint4 rkl = *(const uint4*)(Krb + (size_t)krow * 128 + 64 + kch * 8);
    uint4 rvv = *(const uint4*)(Vth + (size_t)krow * TS + kch * 8);

    for (int j0 = 0; j0 < TS; j0 += 64) {
        __syncthreads();
        *(uint4*)&KhL[krow * 64 + kch * 8] = rkh;
        *(uint4*)&KlL[krow * 64 + kch * 8] = rkl;
        *(uint4*)&VtL[krow * 64 + ksl]     = rvv;
        __syncthreads();

        if (j0 + 64 < TS) {
            const short* kr = Krb + (size_t)(j0 + 64 + krow) * 128;
            rkh = *(const uint4*)(kr + kch * 8);
            rkl = *(const uint4*)(kr + 64 + kch * 8);
            rvv = *(const uint4*)(Vth + (size_t)krow * TS + j0 + 64 + kch * 8);
        }

        f32x4 sc[4];
        #pragma unroll
        for (int t = 0; t < 4; ++t) sc[t] = (f32x4){0.f, 0.f, 0.f, 0.f};
        #pragma unroll
        for (int t = 0; t < 4; ++t) {
            const int rb = (t * 16 + t16) * 64;
            bf16x8 kh0 = *(const bf16x8*)&KhL[rb + cx0];
            bf16x8 kl0 = *(const bf16x8*)&KlL[rb + cx0];
            sc[t] = __builtin_amdgcn_mfma_f32_16x16x32_bf16(qfh[0], kh0, sc[t], 0, 0, 0);
            sc[t] = __builtin_amdgcn_mfma_f32_16x16x32_bf16(qfh[0], kl0, sc[t], 0, 0, 0);
            sc[t] = __builtin_amdgcn_mfma_f32_16x16x32_bf16(qfl[0], kh0, sc[t], 0, 0, 0);
            bf16x8 kh1 = *(const bf16x8*)&KhL[rb + cx1];
            bf16x8 kl1 = *(const bf16x8*)&KlL[rb + cx1];
            sc[t] = __builtin_amdgcn_mfma_f32_16x16x32_bf16(qfh[1], kh1, sc[t], 0, 0, 0);
            sc[t] = __builtin_amdgcn_mfma_f32_16x16x32_bf16(qfh[1], kl1, sc[t], 0, 0, 0);
            sc[t] = __builtin_amdgcn_mfma_f32_16x16x32_bf16(qfl[1], kh1, sc[t], 0, 0, 0);
        }

        #pragma unroll
        for (int t = 0; t < 4; ++t) {
            float p0 = __builtin_amdgcn_exp2f(sc[t][0]);
            float p1 = __builtin_amdgcn_exp2f(sc[t][1]);
            float p2 = __builtin_amdgcn_exp2f(sc[t][2]);
            float p3 = __builtin_amdgcn_exp2f(sc[t][3]);
            lsum[0] += p0; lsum[1] += p1; lsum[2] += p2; lsum[3] += p3;
            const int cb = 2 * t + (t16 >> 3);
            const int co = t16 & 7;
            const int r0 = q0w + quad * 4;
            PsL[(r0 + 0) * 64 + ((cb ^ ((r0 + 0) & 7)) * 8) + co] = bf16s(p0);
            PsL[(r0 + 1) * 64 + ((cb ^ ((r0 + 1) & 7)) * 8) + co] = bf16s(p1);
            PsL[(r0 + 2) * 64 + ((cb ^ ((r0 + 2) & 7)) * 8) + co] = bf16s(p2);
            PsL[(r0 + 3) * 64 + ((cb ^ ((r0 + 3) & 7)) * 8) + co] = bf16s(p3);
        }

        {
            const int pr = (q0w + t16) * 64;
            bf16x8 pa0 = *(const bf16x8*)&PsL[pr + cx0];
            #pragma unroll
            for (int dt = 0; dt < 4; ++dt) {
                bf16x8 vb = *(const bf16x8*)&VtL[(dt * 16 + t16) * 64 + cx0];
                o_acc[dt] = __builtin_amdgcn_mfma_f32_16x16x32_bf16(pa0, vb, o_acc[dt], 0, 0, 0);
            }
            bf16x8 pa1 = *(const bf16x8*)&PsL[pr + cx1];
            #pragma unroll
            for (int dt = 0; dt < 4; ++dt) {
                bf16x8 vb = *(const bf16x8*)&VtL[(dt * 16 + t16) * 64 + cx1];
                o_acc[dt] = __builtin_amdgcn_mfma_f32_16x16x32_bf16(pa1, vb, o_acc[dt], 0, 0, 0);
            }
        }
    }

    #pragma unroll
    for (int r = 0; r < 4; ++r) {
        #pragma unroll
        for (int off = 1; off < 16; off <<= 1)
            lsum[r] += __shfl_xor(lsum[r], off, 16);
    }

    #pragma unroll
    for (int r = 0; r < 4; ++r) {
        const int row = q0 + q0w + quad * 4 + r;
        const float inv = 1.0f / lsum[r];
        #pragma unroll
        for (int dt = 0; dt < 4; ++dt)
            O[((size_t)(b * TS) + row) * TE + h * TD + dt * 16 + t16] = o_acc[dt][r] * inv;
        if (t16 == 0)
            Ls[(size_t)bh * TS + row] = lsum[r];
    }
}

// ----------------------------------------------------------------------------
// attn_avg R5: gload_lds staging of pre-split hi rows (swizzled), XCD remap.
// ----------------------------------------------------------------------------
__global__ __launch_bounds__(256, 2)
void attn_avg_k(const short* __restrict__ Qs, const short* __restrict__ Ks,
                const float* __restrict__ Ls, float* __restrict__ AV)
{
    __shared__ short Qt[128 * 64];
    __shared__ short Kt[128 * 64];
    __shared__ float ML[TH][128];

    const int tid  = threadIdx.x;
    const int lane = tid & 63;
    const int wv   = tid >> 6;
    const int t16  = lane & 15;
    const int quad = lane >> 4;
    const int wq = (wv >> 1) * 64;
    const int wj = (wv & 1) * 64;

    // XCD remap: per XCD one (b, q0-half): Q-tiles L2-resident, K streams
    const int id  = blockIdx.x + 16 * blockIdx.y + 256 * blockIdx.z;
    const int xcd = id & 7;
    const int r_  = id >> 3;                 // 0..127
    const int b   = xcd >> 1;
    const int q0  = ((xcd & 1) * 8 + (r_ >> 4)) * 128;
    const int j0  = (r_ & 15) * 128;

    #pragma unroll
    for (int i = 0; i < 8; ++i) {
        const int u = tid + 256 * i;
        const int h = u >> 7, rr = u & 127;
        ML[h][rr] = 1.0f / Ls[(size_t)(b * TH + h) * TS + q0 + rr];
    }

    const int grow = wv * 8 + (lane >> 3);
    const int gso  = (lane & 7) * 8;
    const int cxh = ((quad) ^ (t16 & 7)) * 8;
    const int cxl = ((4 + quad) ^ (t16 & 7)) * 8;

    f32x4 acc[4][4];
    #pragma unroll
    for (int mt = 0; mt < 4; ++mt)
        #pragma unroll
        for (int nt = 0; nt < 4; ++nt) acc[mt][nt] = (f32x4){0.f, 0.f, 0.f, 0.f};

    for (int h = 0; h < TH; ++h) {
        __syncthreads();   // ML ready (h=0); prev compute done
        const size_t rbq = (size_t)(b * TH + h) * TS + q0;
        const size_t rbk = (size_t)(b * TH + h) * TS + j0;
        #pragma unroll
        for (int r = 0; r < 4; ++r) {
            gl_lds16(Qs + (rbq + r * 32 + grow) * 128 + gso,
                     &Qt[(r * 32 + wv * 8) * 64], lane);
            gl_lds16(Ks + (rbk + r * 32 + grow) * 128 + gso,
                     &Kt[(r * 32 + wv * 8) * 64], lane);
        }
        __syncthreads();

        f32x4 sc[4][4];
        #pragma unroll
        for (int mt = 0; mt < 4; ++mt)
            #pragma unroll
            for (int nt = 0; nt < 4; ++nt) sc[mt][nt] = (f32x4){0.f, 0.f, 0.f, 0.f};
        #pragma unroll
        for (int ks = 0; ks < 2; ++ks) {
            const int cx = ks ? cxl : cxh;
            bf16x8 af[4], bf[4];
            #pragma unroll
            for (int mt = 0; mt < 4; ++mt)
                af[mt] = *(const bf16x8*)&Qt[(wq + mt * 16 + t16) * 64 + cx];
            #pragma unroll
            for (int nt = 0; nt < 4; ++nt)
                bf[nt] = *(const bf16x8*)&Kt[(wj + nt * 16 + t16) * 64 + cx];
            #pragma unroll
            for (int mt = 0; mt < 4; ++mt)
                #pragma unroll
                for (int nt = 0; nt < 4; ++nt)
                    sc[mt][nt] = __builtin_amdgcn_mfma_f32_16x16x32_bf16(af[mt], bf[nt], sc[mt][nt], 0, 0, 0);
        }

        #pragma unroll
        for (int mt = 0; mt < 4; ++mt) {
            const int rl = wq + mt * 16 + quad * 4;
            const float lv[4] = {ML[h][rl], ML[h][rl + 1], ML[h][rl + 2], ML[h][rl + 3]};
            #pragma unroll
            for (int nt = 0; nt < 4; ++nt)
                #pragma unroll
                for (int r = 0; r < 4; ++r)
                    acc[mt][nt][r] = fmaf(__builtin_amdgcn_exp2f(sc[mt][nt][r]), lv[r], acc[mt][nt][r]);
        }
    }

    const float inv_h = 1.0f / (float)TH;
    #pragma unroll
    for (int mt = 0; mt < 4; ++mt) {
        #pragma unroll
        for (int r = 0; r < 4; ++r) {
            const int row = q0 + wq + mt * 16 + quad * 4 + r;
            #pragma unroll
            for (int nt = 0; nt < 4; ++nt) {
                const int col = j0 + wj + nt * 16 + t16;
                AV[((size_t)b * TS + row) * TS + col] = acc[mt][nt][r] * inv_h;
            }
        }
    }
}

// ----------------------------------------------------------------------------
extern "C" void kernel_launch(void* const* d_in, const int* in_sizes, int n_in,
                              void* d_out, int out_size, void* d_ws, size_t ws_size,
                              hipStream_t stream)
{
    const float* query = (const float*)d_in[0];
    const float* key   = (const float*)d_in[1];
    const float* value = (const float*)d_in[2];
    const float* Wq = (const float*)d_in[3];
    const float* bq = (const float*)d_in[4];
    const float* Wk = (const float*)d_in[5];
    const float* bk = (const float*)d_in[6];
    const float* Wv = (const float*)d_in[7];
    const float* bv = (const float*)d_in[8];
    const float* Wo = (const float*)d_in[9];
    const float* bo = (const float*)d_in[10];

    float* ws  = (float*)d_ws;
    float* Qr  = ws + WS_Q;
    float* Kr  = ws + WS_K;
    float* Lsf = ws + WS_L;
    float* tab = ws + WS_TAB;

    float* out  = (float*)d_out;                   // [B,S,E]
    float* attn = out + (size_t)TB * TS * TE;      // [B,S,S] (written last)
    // zones (16.78M floats):
    //   [0, 4.19M):       bf16 V^T [B,H,D,S]      (gemm<2> -> attn_flash)
    //   [4.19M, 12.58M):  Xsp (split inputs) -> Ow fp32 -> Ow split (in-place)
    //   [12.58M, 16.78M): Wsp4 [4][1024][2048]sh  (wsplit -> all GEMMs)
    short* VT   = (short*)attn;
    float* Ow   = attn + 4194304;
    short* Xsp  = (short*)Ow;
    short* Wsp4 = (short*)(attn + 12582912);

    dim3 blk(256);
    dim3 gproj(TE / 128, TM_ / 128);

    wsplit<<<dim3(256), blk, 0, stream>>>(Wq, Wk, Wv, Wo, Wsp4);
    rope_table<<<dim3(256), blk, 0, stream>>>(tab);

    xsplit<<<dim3(512), blk, 0, stream>>>(query, Xsp);
    gemm_nt<1><<<gproj, blk, 0, stream>>>(Xsp, Wsp4,               bq, Qr);
    xsplit<<<dim3(512), blk, 0, stream>>>(key, Xsp);
    gemm_nt<1><<<gproj, blk, 0, stream>>>(Xsp, Wsp4 + 2097152,     bk, Kr);
    xsplit<<<dim3(512), blk, 0, stream>>>(value, Xsp);
    gemm_nt<2><<<gproj, blk, 0, stream>>>(Xsp, Wsp4 + 2 * 2097152, bv, (float*)VT);

    rope_split<<<dim3(1024), blk, 0, stream>>>(Qr, Kr, tab);

    attn_flash<<<dim3(TS / 128, TH, TB), dim3(512), 0, stream>>>(
        (const short*)Qr, (const short*)Kr, VT, Ow, Lsf);

    xsplit<<<dim3(512), blk, 0, stream>>>(Ow, (short*)Ow);   // in-place split
    gemm_nt<0><<<gproj, blk, 0, stream>>>((const short*)Ow, Wsp4 + 3 * 2097152, bo, out);

    attn_avg_k<<<dim3(TS / 128, TS / 128, TB), blk, 0, stream>>>(
        (const short*)Qr, (const short*)Kr, Lsf, attn);
}

// Round 6
// 677.908 us; speedup vs baseline: 1.0662x; 1.0662x over previous
//
#include <hip/hip_runtime.h>
#include <math.h>

// Problem constants
#define TB 4
#define TS 2048
#define TE 1024
#define TH 16
#define TD 64
#define TM_ (TB*TS)   // 8192 rows

// Workspace float offsets
#define WS_Q   0
#define WS_K   8388608
#define WS_L   16777216
#define WS_TAB 16908288

typedef __attribute__((ext_vector_type(8))) short bf16x8;  // 8 bf16 = 4 VGPRs
typedef __attribute__((ext_vector_type(4))) float f32x4;

static __device__ inline unsigned fbits(float x) {
    union { float f; unsigned u; } v; v.f = x; return v.u;
}
static __device__ inline float bits2f(unsigned u) {
    union { unsigned u; float f; } v; v.u = u; return v.f;
}
static __device__ inline unsigned pack_rhu(float a, float b) {
    return __builtin_amdgcn_perm(fbits(b) + 0x8000u, fbits(a) + 0x8000u, 0x07060302u);
}
static __device__ inline short bf16s(float x) {
    return (short)((fbits(x) + 0x8000u) >> 16);
}
// hi/lo split: hp = packed (rounded) hi bf16s, lp = packed lo bf16s
static __device__ inline void split2(float x0, float x1, unsigned& hp, unsigned& lp) {
    unsigned u0 = fbits(x0) + 0x8000u, u1 = fbits(x1) + 0x8000u;
    hp = __builtin_amdgcn_perm(u1, u0, 0x07060302u);
    float h0 = bits2f(u0 & 0xffff0000u);
    float h1 = bits2f(u1 & 0xffff0000u);
    lp = pack_rhu(x0 - h0, x1 - h1);
}

// async 16B/lane global->LDS copy; lds_base is wave-uniform, HW adds lane*16
static __device__ inline void gl_lds16(const short* g, short* lds_base, int lane)
{
#if __has_builtin(__builtin_amdgcn_global_load_lds)
    __builtin_amdgcn_global_load_lds(
        (const __attribute__((address_space(1))) unsigned int*)g,
        (__attribute__((address_space(3))) unsigned int*)lds_base, 16, 0, 0);
#else
    *(uint4*)(lds_base + lane * 8) = *(const uint4*)g;
#endif
}

// ----------------------------------------------------------------------------
// split-row body: 32 fp32 -> merged 64sh tile: slots 0..7 (16B each),
// slot = chunk ^ key; chunks 0-3 = hi of k=c*8..c*8+8, chunks 4-7 = lo.
// ----------------------------------------------------------------------------
static __device__ inline void split_tile(const float* sp, short* dp, int key)
{
    unsigned H[16], L[16];
    #pragma unroll
    for (int c2 = 0; c2 < 8; ++c2) {
        float4 v = *(const float4*)(sp + c2 * 4);
        split2(v.x, v.y, H[2 * c2],     L[2 * c2]);
        split2(v.z, v.w, H[2 * c2 + 1], L[2 * c2 + 1]);
    }
    #pragma unroll
    for (int c = 0; c < 4; ++c) {
        *(uint4*)(dp + ((c ^ key) * 8)) =
            make_uint4(H[4 * c], H[4 * c + 1], H[4 * c + 2], H[4 * c + 3]);
        *(uint4*)(dp + (((4 + c) ^ key) * 8)) =
            make_uint4(L[4 * c], L[4 * c + 1], L[4 * c + 2], L[4 * c + 3]);
    }
}

// wsplit: 4 weight matrices -> [4][1024][32 kt][8 slots * 8sh], key = n&7
__global__ __launch_bounds__(256, 4)
void wsplit(const float* __restrict__ W0, const float* __restrict__ W1,
            const float* __restrict__ W2, const float* __restrict__ W3,
            short* __restrict__ dst)
{
    const int idx = blockIdx.x * 256 + threadIdx.x;   // 65536
    const int kt = idx & 15;
    const int row = idx >> 4;                          // 0..4095
    const int w = row >> 10, n = row & 1023;
    const float* Wx = (w == 0) ? W0 : (w == 1) ? W1 : (w == 2) ? W2 : W3;
    const float* sp = Wx + (size_t)n * 1024 + kt * 64;
    short* dp = dst + (size_t)row * 2048 + kt * 128;
    const int key = n & 7;
    split_tile(sp,      dp,      key);
    split_tile(sp + 32, dp + 64, key);
}

// ----------------------------------------------------------------------------
// GEMM R6: fp32 X + pre-split W; T14 reg-prefetch of BOTH operands (loads for
// kt+1 issue right after barrier 2 and retire under the 48-MFMA phase; the A
// hi/lo split runs at the TOP of the next iteration, before barrier 1).
// Merged [128][64]sh XOR-swizzled LDS (R5-verified layout). XCD-clustered grid.
// MODE 0: fp32 out[m*N+n]; MODE 1: fp32 [B,H,S,D]; MODE 2: bf16 V^T [B,H,D,S]
// ----------------------------------------------------------------------------
template<int MODE>
__global__ __launch_bounds__(256, 3)
void gemm_nt(const float* __restrict__ X, const short* __restrict__ Ws,
             const float* __restrict__ bias, float* __restrict__ out)
{
    __shared__ short A2[128 * 64];
    __shared__ short B2[128 * 64];

    const int tid  = threadIdx.x;
    const int lane = tid & 63;
    const int wv   = tid >> 6;
    const int t16  = lane & 15;
    const int quad = lane >> 4;
    const int wm   = (wv >> 1) * 64;
    const int wn   = (wv & 1) * 64;

    // XCD-cluster (R3-proven): 512 blocks; XCD k owns m-panels [8k, 8k+8),
    // all 8 n-panels of a m-panel on the same XCD -> X-panel L2-resident.
    const int id  = blockIdx.x + 8 * blockIdx.y;     // grid (8, 64)
    const int xcd = id & 7;
    const int i_  = id >> 3;                          // 0..63
    const int m0  = (xcd * 8 + (i_ >> 3)) * 128;
    const int n0  = (i_ & 7) * 128;

    // staging: thread -> row = tid>>1 (0..127), half = tid&1
    const int arow = tid >> 1;
    const int akh  = tid & 1;                 // A: k in [akh*16, akh*16+16)
    const int akey = arow & 7;
    const float* Xp = X + (size_t)(m0 + arow) * 1024 + akh * 16;
    const short* Wp = Ws + (size_t)(n0 + arow) * 2048 + akh * 32;

    const int cxh = ((quad) ^ (t16 & 7)) * 8;
    const int cxl = ((4 + quad) ^ (t16 & 7)) * 8;

    f32x4 acc[4][4];
    #pragma unroll
    for (int i = 0; i < 4; ++i)
        #pragma unroll
        for (int j = 0; j < 4; ++j) acc[i][j] = (f32x4){0.f, 0.f, 0.f, 0.f};

    // prologue: load kt=0 operands into registers
    float4 ax0 = *(const float4*)(Xp);
    float4 ax1 = *(const float4*)(Xp + 4);
    float4 ax2 = *(const float4*)(Xp + 8);
    float4 ax3 = *(const float4*)(Xp + 12);
    uint4  bx0 = *(const uint4*)(Wp);
    uint4  bx1 = *(const uint4*)(Wp + 8);
    uint4  bx2 = *(const uint4*)(Wp + 16);
    uint4  bx3 = *(const uint4*)(Wp + 24);

    for (int kt = 0; kt < 32; ++kt) {
        // split A regs (data for THIS kt) — overlaps other waves' MFMA tail
        unsigned H[8], L[8];
        split2(ax0.x, ax0.y, H[0], L[0]);
        split2(ax0.z, ax0.w, H[1], L[1]);
        split2(ax1.x, ax1.y, H[2], L[2]);
        split2(ax1.z, ax1.w, H[3], L[3]);
        split2(ax2.x, ax2.y, H[4], L[4]);
        split2(ax2.z, ax2.w, H[5], L[5]);
        split2(ax3.x, ax3.y, H[6], L[6]);
        split2(ax3.z, ax3.w, H[7], L[7]);

        __syncthreads();   // prev iter's LDS reads done
        *(uint4*)&A2[arow * 64 + (((2 * akh + 0) ^ akey) * 8)] = make_uint4(H[0], H[1], H[2], H[3]);
        *(uint4*)&A2[arow * 64 + (((2 * akh + 1) ^ akey) * 8)] = make_uint4(H[4], H[5], H[6], H[7]);
        *(uint4*)&A2[arow * 64 + (((4 + 2 * akh + 0) ^ akey) * 8)] = make_uint4(L[0], L[1], L[2], L[3]);
        *(uint4*)&A2[arow * 64 + (((4 + 2 * akh + 1) ^ akey) * 8)] = make_uint4(L[4], L[5], L[6], L[7]);
        *(uint4*)&B2[arow * 64 + akh * 32 + 0]  = bx0;
        *(uint4*)&B2[arow * 64 + akh * 32 + 8]  = bx1;
        *(uint4*)&B2[arow * 64 + akh * 32 + 16] = bx2;
        *(uint4*)&B2[arow * 64 + akh * 32 + 24] = bx3;
        __syncthreads();

        // T14: issue kt+1 loads now; they retire under the MFMA phase
        if (kt + 1 < 32) {
            const float* xp = Xp + (kt + 1) * 32;
            ax0 = *(const float4*)(xp);
            ax1 = *(const float4*)(xp + 4);
            ax2 = *(const float4*)(xp + 8);
            ax3 = *(const float4*)(xp + 12);
            const short* wp = Wp + (kt + 1) * 64;
            bx0 = *(const uint4*)(wp);
            bx1 = *(const uint4*)(wp + 8);
            bx2 = *(const uint4*)(wp + 16);
            bx3 = *(const uint4*)(wp + 24);
        }

        bf16x8 ah[4], al[4], bh[4], bl[4];
        #pragma unroll
        for (int i = 0; i < 4; ++i) {
            ah[i] = *(const bf16x8*)&A2[(wm + i * 16 + t16) * 64 + cxh];
            al[i] = *(const bf16x8*)&A2[(wm + i * 16 + t16) * 64 + cxl];
            bh[i] = *(const bf16x8*)&B2[(wn + i * 16 + t16) * 64 + cxh];
            bl[i] = *(const bf16x8*)&B2[(wn + i * 16 + t16) * 64 + cxl];
        }
        #pragma unroll
        for (int i = 0; i < 4; ++i)
            #pragma unroll
            for (int j = 0; j < 4; ++j) {
                acc[i][j] = __builtin_amdgcn_mfma_f32_16x16x32_bf16(ah[i], bh[j], acc[i][j], 0, 0, 0);
                acc[i][j] = __builtin_amdgcn_mfma_f32_16x16x32_bf16(al[i], bh[j], acc[i][j], 0, 0, 0);
                acc[i][j] = __builtin_amdgcn_mfma_f32_16x16x32_bf16(ah[i], bl[j], acc[i][j], 0, 0, 0);
            }
    }

    if (MODE == 2) {
        short* o16 = (short*)out;
        const int b = m0 >> 11;
        const int sbase0 = (m0 & 2047) + wm + quad * 4;
        #pragma unroll
        for (int j = 0; j < 4; ++j) {
            const int n = n0 + wn + j * 16 + t16;
            const int h = n >> 6, d = n & 63;
            const float bv = bias[n];
            const size_t base = ((size_t)(b * TH + h) * TD + d) * TS;
            #pragma unroll
            for (int i = 0; i < 4; ++i) {
                const int s = sbase0 + i * 16;
                uint2 p = make_uint2(pack_rhu(acc[i][j][0] + bv, acc[i][j][1] + bv),
                                     pack_rhu(acc[i][j][2] + bv, acc[i][j][3] + bv));
                *(uint2*)(o16 + base + s) = p;
            }
        }
        return;
    }

    #pragma unroll
    for (int j = 0; j < 4; ++j) {
        const int n = n0 + wn + j * 16 + t16;
        const float bv = bias[n];
        if (MODE == 0) {
            #pragma unroll
            for (int i = 0; i < 4; ++i)
                #pragma unroll
                for (int r = 0; r < 4; ++r) {
                    const int m = m0 + wm + i * 16 + quad * 4 + r;
                    out[(size_t)m * TE + n] = acc[i][j][r] + bv;
                }
        } else {
            const int h = n >> 6, d = n & 63;
            #pragma unroll
            for (int i = 0; i < 4; ++i)
                #pragma unroll
                for (int r = 0; r < 4; ++r) {
                    const int m = m0 + wm + i * 16 + quad * 4 + r;
                    const int bb_ = m >> 11, s = m & 2047;
                    out[((size_t)(bb_ * TH + h) * TS + s) * TD + d] = acc[i][j][r] + bv;
                }
        }
    }
}

// ----------------------------------------------------------------------------
__global__ void rope_table(float* __restrict__ tab)
{
    const int idx = blockIdx.x * 256 + threadIdx.x;
    const int d = idx & 31, s = idx >> 5;
    const float e = (float)(2 * d) / 64.0f;
    const float inv = 1.0f / powf(10000.0f, e);
    const float a = (float)s * inv;
    tab[2 * idx + 0] = cosf(a);
    tab[2 * idx + 1] = sinf(a);
}

// ----------------------------------------------------------------------------
// rope_split: in-place RoPE (+Q scale) then hi/lo split; BOTH Q and K rows
// chunk-swizzled (slot = ch ^ (s&7)) within each 64-short half.
// ----------------------------------------------------------------------------
__global__ __launch_bounds__(256, 2)
void rope_split(float* __restrict__ Q, float* __restrict__ Kv,
                const float* __restrict__ tab)
{
    const int idx = blockIdx.x * 256 + threadIdx.x;    // 262144 rows
    const int s  = idx & 2047;
    const int bh = (idx >> 11) & 63;
    const int qk = idx >> 17;
    float* P = qk ? Kv : Q;
    const float scale = qk ? 1.0f : (0.125f * 1.44269504f);
    const int key = s & 7;
    unsigned* rp = (unsigned*)(P + ((size_t)bh * TS + s) * 64);

    unsigned xu[64];
    #pragma unroll
    for (int i = 0; i < 16; ++i) {
        uint4 v = *(const uint4*)(rp + i * 4);
        xu[4 * i + 0] = v.x; xu[4 * i + 1] = v.y;
        xu[4 * i + 2] = v.z; xu[4 * i + 3] = v.w;
    }
    const float* tb = tab + (size_t)s * 64;
    #pragma unroll
    for (int d = 0; d < 32; ++d) {
        const float c = tb[2 * d], sn = tb[2 * d + 1];
        const float x0 = bits2f(xu[d]), x1 = bits2f(xu[d + 32]);
        xu[d]      = fbits((x0 * c - x1 * sn) * scale);
        xu[d + 32] = fbits((x1 * c + x0 * sn) * scale);
    }
    #pragma unroll
    for (int ch = 0; ch < 8; ++ch) {
        unsigned h[4], l[4];
        #pragma unroll
        for (int p = 0; p < 4; ++p)
            split2(bits2f(xu[ch * 8 + 2 * p]), bits2f(xu[ch * 8 + 2 * p + 1]), h[p], l[p]);
        const int slot = ch ^ key;
        *(uint4*)(rp + slot * 4)      = make_uint4(h[0], h[1], h[2], h[3]);
        *(uint4*)(rp + 32 + slot * 4) = make_uint4(l[0], l[1], l[2], l[3]);
    }
}

// ----------------------------------------------------------------------------
// Flash attention (R5-verified, unchanged): pre-split swizzled Q/K, T14 reg
// prefetch, XCD-clustered remap, conflict-free swizzled LDS.
// ----------------------------------------------------------------------------
__global__ __launch_bounds__(512, 4)
void attn_flash(const short* __restrict__ Qs, const short* __restrict__ Ks,
                const short* __restrict__ VT, float* __restrict__ O,
                float* __restrict__ Ls)
{
    __shared__ short KhL[4096], KlL[4096];
    __shared__ short VtL[4096];
    __shared__ short PsL[8192];

    const int tid  = threadIdx.x;
    const int lane = tid & 63;
    const int wv   = tid >> 6;
    const int t16  = lane & 15;
    const int quad = lane >> 4;
    const int q0w  = wv * 16;

    const int L   = blockIdx.x + 16 * blockIdx.y + 256 * blockIdx.z;
    const int xcd = L & 7;
    const int i_  = L >> 3;
    const int qt  = i_ & 15;
    const int g   = (xcd << 3) | (i_ >> 4);
    const int h   = g & 15;
    const int b   = g >> 4;

    const int q0 = qt * 128;
    const int bh = b * TH + h;
    const short* Krb = Ks + (size_t)bh * TS * 128;
    const short* Vth = VT + (size_t)bh * TD * TS;

    const int cx0 = ((quad) ^ (t16 & 7)) * 8;
    const int cx1 = ((4 + quad) ^ (t16 & 7)) * 8;

    bf16x8 qfh[2], qfl[2];
    {
        const short* qrow = Qs + ((size_t)bh * TS + q0 + q0w + t16) * 128;
        qfh[0] = *(const bf16x8*)(qrow + cx0);
        qfh[1] = *(const bf16x8*)(qrow + cx1);
        qfl[0] = *(const bf16x8*)(qrow + 64 + cx0);
        qfl[1] = *(const bf16x8*)(qrow + 64 + cx1);
    }

    float lsum[4] = {0.f, 0.f, 0.f, 0.f};
    f32x4 o_acc[4];
    #pragma unroll
    for (int dt = 0; dt < 4; ++dt) o_acc[dt] = (f32x4){0.f, 0.f, 0.f, 0.f};

    const int krow = tid >> 3;
    const int kch  = tid & 7;
    const int ksl  = (kch ^ (krow & 7)) * 8;

    uint4 rkh = *(const uint4*)(Krb + (size_t)krow * 128 + kch * 8);
    uint4 rkl = *(const uint4*)(Krb + (size_t)krow * 128 + 64 + kch * 8);
    uint4 rvv = *(const uint4*)(Vth + (size_t)krow * TS + kch * 8);

    for (int j0 = 0; j0 < TS; j0 += 64) {
        __syncthreads();
        *(uint4*)&KhL[krow * 64 + kch * 8] = rkh;
        *(uint4*)&KlL[krow * 64 + kch * 8] = rkl;
        *(uint4*)&VtL[krow * 64 + ksl]     = rvv;
        __syncthreads();

        if (j0 + 64 < TS) {
            const short* kr = Krb + (size_t)(j0 + 64 + krow) * 128;
            rkh = *(const uint4*)(kr + kch * 8);
            rkl = *(const uint4*)(kr + 64 + kch * 8);
            rvv = *(const uint4*)(Vth + (size_t)krow * TS + j0 + 64 + kch * 8);
        }

        f32x4 sc[4];
        #pragma unroll
        for (int t = 0; t < 4; ++t) sc[t] = (f32x4){0.f, 0.f, 0.f, 0.f};
        #pragma unroll
        for (int t = 0; t < 4; ++t) {
            const int rb = (t * 16 + t16) * 64;
            bf16x8 kh0 = *(const bf16x8*)&KhL[rb + cx0];
            bf16x8 kl0 = *(const bf16x8*)&KlL[rb + cx0];
            sc[t] = __builtin_amdgcn_mfma_f32_16x16x32_bf16(qfh[0], kh0, sc[t], 0, 0, 0);
            sc[t] = __builtin_amdgcn_mfma_f32_16x16x32_bf16(qfh[0], kl0, sc[t], 0, 0, 0);
            sc[t] = __builtin_amdgcn_mfma_f32_16x16x32_bf16(qfl[0], kh0, sc[t], 0, 0, 0);
            bf16x8 kh1 = *(const bf16x8*)&KhL[rb + cx1];
            bf16x8 kl1 = *(const bf16x8*)&KlL[rb + cx1];
            sc[t] = __builtin_amdgcn_mfma_f32_16x16x32_bf16(qfh[1], kh1, sc[t], 0, 0, 0);
            sc[t] = __builtin_amdgcn_mfma_f32_16x16x32_bf16(qfh[1], kl1, sc[t], 0, 0, 0);
            sc[t] = __builtin_amdgcn_mfma_f32_16x16x32_bf16(qfl[1], kh1, sc[t], 0, 0, 0);
        }

        #pragma unroll
        for (int t = 0; t < 4; ++t) {
            float p0 = __builtin_amdgcn_exp2f(sc[t][0]);
            float p1 = __builtin_amdgcn_exp2f(sc[t][1]);
            float p2 = __builtin_amdgcn_exp2f(sc[t][2]);
            float p3 = __builtin_amdgcn_exp2f(sc[t][3]);
            lsum[0] += p0; lsum[1] += p1; lsum[2] += p2; lsum[3] += p3;
            const int cb = 2 * t + (t16 >> 3);
            const int co = t16 & 7;
            const int r0 = q0w + quad * 4;
            PsL[(r0 + 0) * 64 + ((cb ^ ((r0 + 0) & 7)) * 8) + co] = bf16s(p0);
            PsL[(r0 + 1) * 64 + ((cb ^ ((r0 + 1) & 7)) * 8) + co] = bf16s(p1);
            PsL[(r0 + 2) * 64 + ((cb ^ ((r0 + 2) & 7)) * 8) + co] = bf16s(p2);
            PsL[(r0 + 3) * 64 + ((cb ^ ((r0 + 3) & 7)) * 8) + co] = bf16s(p3);
        }

        {
            const int pr = (q0w + t16) * 64;
            bf16x8 pa0 = *(const bf16x8*)&PsL[pr + cx0];
            #pragma unroll
            for (int dt = 0; dt < 4; ++dt) {
                bf16x8 vb = *(const bf16x8*)&VtL[(dt * 16 + t16) * 64 + cx0];
                o_acc[dt] = __builtin_amdgcn_mfma_f32_16x16x32_bf16(pa0, vb, o_acc[dt], 0, 0, 0);
            }
            bf16x8 pa1 = *(const bf16x8*)&PsL[pr + cx1];
            #pragma unroll
            for (int dt = 0; dt < 4; ++dt) {
                bf16x8 vb = *(const bf16x8*)&VtL[(dt * 16 + t16) * 64 + cx1];
                o_acc[dt] = __builtin_amdgcn_mfma_f32_16x16x32_bf16(pa1, vb, o_acc[dt], 0, 0, 0);
            }
        }
    }

    #pragma unroll
    for (int r = 0; r < 4; ++r) {
        #pragma unroll
        for (int off = 1; off < 16; off <<= 1)
            lsum[r] += __shfl_xor(lsum[r], off, 16);
    }

    #pragma unroll
    for (int r = 0; r < 4; ++r) {
        const int row = q0 + q0w + quad * 4 + r;
        const float inv = 1.0f / lsum[r];
        #pragma unroll
        for (int dt = 0; dt < 4; ++dt)
            O[((size_t)(b * TS) + row) * TE + h * TD + dt * 16 + t16] = o_acc[dt][r] * inv;
        if (t16 == 0)
            Ls[(size_t)bh * TS + row] = lsum[r];
    }
}

// ----------------------------------------------------------------------------
// attn_avg (R5-verified, unchanged): gload_lds staging of pre-split hi rows,
// swizzled reads, XCD remap.
// ----------------------------------------------------------------------------
__global__ __launch_bounds__(256, 2)
void attn_avg_k(const short* __restrict__ Qs, const short* __restrict__ Ks,
                const float* __restrict__ Ls, float* __restrict__ AV)
{
    __shared__ short Qt[128 * 64];
    __shared__ short Kt[128 * 64];
    __shared__ float ML[TH][128];

    const int tid  = threadIdx.x;
    const int lane = tid & 63;
    const int wv   = tid >> 6;
    const int t16  = lane & 15;
    const int quad = lane >> 4;
    const int wq = (wv >> 1) * 64;
    const int wj = (wv & 1) * 64;

    const int id  = blockIdx.x + 16 * blockIdx.y + 256 * blockIdx.z;
    const int xcd = id & 7;
    const int r_  = id >> 3;
    const int b   = xcd >> 1;
    const int q0  = ((xcd & 1) * 8 + (r_ >> 4)) * 128;
    const int j0  = (r_ & 15) * 128;

    #pragma unroll
    for (int i = 0; i < 8; ++i) {
        const int u = tid + 256 * i;
        const int h = u >> 7, rr = u & 127;
        ML[h][rr] = 1.0f / Ls[(size_t)(b * TH + h) * TS + q0 + rr];
    }

    const int grow = wv * 8 + (lane >> 3);
    const int gso  = (lane & 7) * 8;
    const int cxh = ((quad) ^ (t16 & 7)) * 8;
    const int cxl = ((4 + quad) ^ (t16 & 7)) * 8;

    f32x4 acc[4][4];
    #pragma unroll
    for (int mt = 0; mt < 4; ++mt)
        #pragma unroll
        for (int nt = 0; nt < 4; ++nt) acc[mt][nt] = (f32x4){0.f, 0.f, 0.f, 0.f};

    for (int h = 0; h < TH; ++h) {
        __syncthreads();
        const size_t rbq = (size_t)(b * TH + h) * TS + q0;
        const size_t rbk = (size_t)(b * TH + h) * TS + j0;
        #pragma unroll
        for (int r = 0; r < 4; ++r) {
            gl_lds16(Qs + (rbq + r * 32 + grow) * 128 + gso,
                     &Qt[(r * 32 + wv * 8) * 64], lane);
            gl_lds16(Ks + (rbk + r * 32 + grow) * 128 + gso,
                     &Kt[(r * 32 + wv * 8) * 64], lane);
        }
        __syncthreads();

        f32x4 sc[4][4];
        #pragma unroll
        for (int mt = 0; mt < 4; ++mt)
            #pragma unroll
            for (int nt = 0; nt < 4; ++nt) sc[mt][nt] = (f32x4){0.f, 0.f, 0.f, 0.f};
        #pragma unroll
        for (int ks = 0; ks < 2; ++ks) {
            const int cx = ks ? cxl : cxh;
            bf16x8 af[4], bf[4];
            #pragma unroll
            for (int mt = 0; mt < 4; ++mt)
                af[mt] = *(const bf16x8*)&Qt[(wq + mt * 16 + t16) * 64 + cx];
            #pragma unroll
            for (int nt = 0; nt < 4; ++nt)
                bf[nt] = *(const bf16x8*)&Kt[(wj + nt * 16 + t16) * 64 + cx];
            #pragma unroll
            for (int mt = 0; mt < 4; ++mt)
                #pragma unroll
                for (int nt = 0; nt < 4; ++nt)
                    sc[mt][nt] = __builtin_amdgcn_mfma_f32_16x16x32_bf16(af[mt], bf[nt], sc[mt][nt], 0, 0, 0);
        }

        #pragma unroll
        for (int mt = 0; mt < 4; ++mt) {
            const int rl = wq + mt * 16 + quad * 4;
            const float lv[4] = {ML[h][rl], ML[h][rl + 1], ML[h][rl + 2], ML[h][rl + 3]};
            #pragma unroll
            for (int nt = 0; nt < 4; ++nt)
                #pragma unroll
                for (int r = 0; r < 4; ++r)
                    acc[mt][nt][r] = fmaf(__builtin_amdgcn_exp2f(sc[mt][nt][r]), lv[r], acc[mt][nt][r]);
        }
    }

    const float inv_h = 1.0f / (float)TH;
    #pragma unroll
    for (int mt = 0; mt < 4; ++mt) {
        #pragma unroll
        for (int r = 0; r < 4; ++r) {
            const int row = q0 + wq + mt * 16 + quad * 4 + r;
            #pragma unroll
            for (int nt = 0; nt < 4; ++nt) {
                const int col = j0 + wj + nt * 16 + t16;
                AV[((size_t)b * TS + row) * TS + col] = acc[mt][nt][r] * inv_h;
            }
        }
    }
}

// ----------------------------------------------------------------------------
extern "C" void kernel_launch(void* const* d_in, const int* in_sizes, int n_in,
                              void* d_out, int out_size, void* d_ws, size_t ws_size,
                              hipStream_t stream)
{
    const float* query = (const float*)d_in[0];
    const float* key   = (const float*)d_in[1];
    const float* value = (const float*)d_in[2];
    const float* Wq = (const float*)d_in[3];
    const float* bq = (const float*)d_in[4];
    const float* Wk = (const float*)d_in[5];
    const float* bk = (const float*)d_in[6];
    const float* Wv = (const float*)d_in[7];
    const float* bv = (const float*)d_in[8];
    const float* Wo = (const float*)d_in[9];
    const float* bo = (const float*)d_in[10];

    float* ws  = (float*)d_ws;
    float* Qr  = ws + WS_Q;
    float* Kr  = ws + WS_K;
    float* Lsf = ws + WS_L;
    float* tab = ws + WS_TAB;

    float* out  = (float*)d_out;                   // [B,S,E]
    float* attn = out + (size_t)TB * TS * TE;      // [B,S,S] (written last)
    // zones (16.78M floats):
    //   [0, 4.19M):       bf16 V^T [B,H,D,S]      (gemm<2> -> attn_flash)
    //   [4.19M, 12.58M):  fp32 Ow [B,S,E]         (attn_flash -> Wo GEMM)
    //   [12.58M, 16.78M): Wsp4 [4][1024][2048]sh  (wsplit -> all GEMMs)
    short* VT   = (short*)attn;
    float* Ow   = attn + 4194304;
    short* Wsp4 = (short*)(attn + 12582912);

    dim3 blk(256);
    dim3 gproj(TE / 128, TM_ / 128);

    wsplit<<<dim3(256), blk, 0, stream>>>(Wq, Wk, Wv, Wo, Wsp4);
    rope_table<<<dim3(256), blk, 0, stream>>>(tab);

    gemm_nt<1><<<gproj, blk, 0, stream>>>(query, Wsp4,               bq, Qr);
    gemm_nt<1><<<gproj, blk, 0, stream>>>(key,   Wsp4 + 2097152,     bk, Kr);
    gemm_nt<2><<<gproj, blk, 0, stream>>>(value, Wsp4 + 2 * 2097152, bv, (float*)VT);

    rope_split<<<dim3(1024), blk, 0, stream>>>(Qr, Kr, tab);

    attn_flash<<<dim3(TS / 128, TH, TB), dim3(512), 0, stream>>>(
        (const short*)Qr, (const short*)Kr, VT, Ow, Lsf);

    gemm_nt<0><<<gproj, blk, 0, stream>>>(Ow, Wsp4 + 3 * 2097152, bo, out);

    attn_avg_k<<<dim3(TS / 128, TS / 128, TB), blk, 0, stream>>>(
        (const short*)Qr, (const short*)Kr, Lsf, attn);
}